// Round 15
// baseline (46.283 us; speedup 1.0000x reference)
//
#include <hip/hip_runtime.h>

// Problem constants (match reference)
#define NN    20000
#define EDGES 320000
#define HH    8
#define CC    120
#define HC    960
#define SLOPE 0.2f
#define BUCKET 64   // max in-degree bound (Poisson(16); P(>64) ~ 1e-20)

// U column layout (per k row of U[128][32]):  c = 4h+0 -> W_h@att_src[h] (as)
//   c = 4h+1 -> W_h@fc_w[:,0] slice h (z0);  c = 4h+2 -> W_h@fc_w[:,1] (z1)
//   c = 4h+3 -> W_h@att_dst[h] (ad)
// => P row n: [as,z0,z1,ad] x 8 heads; gather reads ONE float4 per (edge,head).
//
// R15 structure: prep -> scatter (max-TLP, isolated atomics) -> proj -> gather.
// Rationale: in the fused kernel the pre-__syncthreads s_waitcnt vmcnt(0)
// drained the 4 contended returning atomics per thread at 1.2 waves/SIMD
// (no TLP to hide); a dedicated 320K-thread scatter hides them fully.

// ---------------------------------------------------------------------------
// K1 prep: grid 257 x 256.  (R12 verbatim)
// ---------------------------------------------------------------------------
__global__ __launch_bounds__(256) void prep_kernel(const float* __restrict__ W,
                                                   const float* __restrict__ att_src,
                                                   const float* __restrict__ att_dst,
                                                   const float* __restrict__ bias,
                                                   const float* __restrict__ fc_w,
                                                   const float* __restrict__ fc_b,
                                                   float* __restrict__ U,
                                                   float* __restrict__ cbias,
                                                   unsigned* __restrict__ cnt) {
  int t = threadIdx.x, b = blockIdx.x;
  int gid = b * 256 + t;
  if (gid < NN) cnt[gid] = 0u;

  int l = t & 63;
  if (b < 256) {
    int p = b * 4 + (t >> 6);        // 0..1023
    int k = p >> 3, h = p & 7;
    const float* wrow = W + (size_t)k * HC + h * CC;
    const float* asv  = att_src + h * CC;
    const float* adv  = att_dst + h * CC;
    const float2* fv  = (const float2*)fc_w + h * CC;
    bool tail = (l < CC - 64);       // l < 56
    float w0 = wrow[l],            w1 = tail ? wrow[64 + l] : 0.f;
    float s0 = asv[l],             s1 = tail ? asv[64 + l] : 0.f;
    float d0 = adv[l],             d1 = tail ? adv[64 + l] : 0.f;
    float2 f0 = fv[l];
    float2 f1 = tail ? fv[64 + l] : make_float2(0.f, 0.f);
    float a_s = w0 * s0 + w1 * s1;
    float a_d = w0 * d0 + w1 * d1;
    float z0  = w0 * f0.x + w1 * f1.x;
    float z1  = w0 * f0.y + w1 * f1.y;
#pragma unroll
    for (int m = 1; m < 64; m <<= 1) {
      a_s += __shfl_xor(a_s, m);
      a_d += __shfl_xor(a_d, m);
      z0  += __shfl_xor(z0, m);
      z1  += __shfl_xor(z1, m);
    }
    if (l == 0) {
      float* u = U + k * 32 + 4 * h;
      u[0] = a_s; u[1] = z0; u[2] = z1; u[3] = a_d;
    }
  } else if (b == 256 && t < 128) {
    int j = t >> 6;                  // 0 or 1
    float acc = 0.f;
    for (int m = l; m < HC; m += 64) acc = fmaf(bias[m], fc_w[m * 2 + j], acc);
#pragma unroll
    for (int m = 1; m < 64; m <<= 1) acc += __shfl_xor(acc, m);
    if (l == 0) cbias[j] = acc + fc_b[j];
  }
}

// ---------------------------------------------------------------------------
// K2 scatter: grid 1250 x 256, ONE edge per thread (320K threads co-resident:
// ~16 waves/SIMD of TLP hides the contended atomic round-trips).
// ---------------------------------------------------------------------------
__global__ __launch_bounds__(256) void scatter_kernel(const int* __restrict__ ei,
                                                      unsigned* __restrict__ cnt,
                                                      unsigned* __restrict__ list) {
  int g = blockIdx.x * 256 + threadIdx.x;   // 1250*256 == 320000 exactly
  int s = ei[g];
  int d = ei[EDGES + g];
  unsigned slot = atomicAdd(&cnt[d], 1u);
  list[(size_t)d * BUCKET + slot] = (unsigned)s;
}

// ---------------------------------------------------------------------------
// K3 proj: grid 625 x 128.  (R12's proj verbatim, scatter removed — barrier
// now only drains the fast x/U staging loads.)
// ---------------------------------------------------------------------------
#define XSTR 132
__global__ __launch_bounds__(128) void proj_kernel(const float* __restrict__ x,
                                                   const float* __restrict__ U,
                                                   float* __restrict__ P) {
  __shared__ float xs[32 * XSTR];    // 32 rows x 128 (+4 pad)
  __shared__ float Us[128 * 32];
  int t = threadIdx.x;
  int b = blockIdx.x;
  int n0 = b * 32;

  const float4* xg = (const float4*)(x + (size_t)n0 * 128);
  const float4* U4 = (const float4*)U;
  float4 xv[8], uv[8];
#pragma unroll
  for (int j = 0; j < 8; ++j) xv[j] = xg[t + j * 128];
#pragma unroll
  for (int j = 0; j < 8; ++j) uv[j] = U4[t + j * 128];
#pragma unroll
  for (int j = 0; j < 8; ++j) {
    int i = t + j * 128;
    *(float4*)(xs + (i >> 5) * XSTR + (i & 31) * 4) = xv[j];
    ((float4*)Us)[i] = uv[j];
  }
  __syncthreads();

  int rq = t >> 3, cq = t & 7;       // rows {rq, rq+16}, col-quad cq
  float a00 = 0.f, a01 = 0.f, a02 = 0.f, a03 = 0.f;
  float a10 = 0.f, a11 = 0.f, a12 = 0.f, a13 = 0.f;
  const float* xr0 = xs + rq * XSTR;
  const float* xr1 = xs + (rq + 16) * XSTR;
#pragma unroll 4
  for (int k4 = 0; k4 < 32; ++k4) {
    float4 xa = *(const float4*)(xr0 + k4 * 4);
    float4 xb = *(const float4*)(xr1 + k4 * 4);
    float4 u0 = *(const float4*)(Us + (k4 * 4 + 0) * 32 + 4 * cq);
    float4 u1 = *(const float4*)(Us + (k4 * 4 + 1) * 32 + 4 * cq);
    float4 u2 = *(const float4*)(Us + (k4 * 4 + 2) * 32 + 4 * cq);
    float4 u3 = *(const float4*)(Us + (k4 * 4 + 3) * 32 + 4 * cq);
    a00 = fmaf(xa.x, u0.x, a00); a01 = fmaf(xa.x, u0.y, a01);
    a02 = fmaf(xa.x, u0.z, a02); a03 = fmaf(xa.x, u0.w, a03);
    a10 = fmaf(xb.x, u0.x, a10); a11 = fmaf(xb.x, u0.y, a11);
    a12 = fmaf(xb.x, u0.z, a12); a13 = fmaf(xb.x, u0.w, a13);
    a00 = fmaf(xa.y, u1.x, a00); a01 = fmaf(xa.y, u1.y, a01);
    a02 = fmaf(xa.y, u1.z, a02); a03 = fmaf(xa.y, u1.w, a03);
    a10 = fmaf(xb.y, u1.x, a10); a11 = fmaf(xb.y, u1.y, a11);
    a12 = fmaf(xb.y, u1.z, a12); a13 = fmaf(xb.y, u1.w, a13);
    a00 = fmaf(xa.z, u2.x, a00); a01 = fmaf(xa.z, u2.y, a01);
    a02 = fmaf(xa.z, u2.z, a02); a03 = fmaf(xa.z, u2.w, a03);
    a10 = fmaf(xb.z, u2.x, a10); a11 = fmaf(xb.z, u2.y, a11);
    a12 = fmaf(xb.z, u2.z, a12); a13 = fmaf(xb.z, u2.w, a13);
    a00 = fmaf(xa.w, u3.x, a00); a01 = fmaf(xa.w, u3.y, a01);
    a02 = fmaf(xa.w, u3.z, a02); a03 = fmaf(xa.w, u3.w, a03);
    a10 = fmaf(xb.w, u3.x, a10); a11 = fmaf(xb.w, u3.y, a11);
    a12 = fmaf(xb.w, u3.z, a12); a13 = fmaf(xb.w, u3.w, a13);
  }
  *(float4*)(P + (size_t)(n0 + rq) * 32 + 4 * cq) =
      make_float4(a00, a01, a02, a03);
  *(float4*)(P + (size_t)(n0 + rq + 16) * 32 + 4 * cq) =
      make_float4(a10, a11, a12, a13);
}

// ---------------------------------------------------------------------------
// K4 gather: ONE WAVE per dst (R12 verbatim).
// ---------------------------------------------------------------------------
__global__ __launch_bounds__(256) void gather_kernel(const unsigned* __restrict__ cnt,
                                                     const unsigned* __restrict__ list,
                                                     const float* __restrict__ P,
                                                     const float* __restrict__ cbias,
                                                     float* __restrict__ out) {
  int t = threadIdx.x;
  int wave = t >> 6;           // 0..3
  int lane = t & 63;
  int h = lane & 7;            // head
  int o = lane >> 3;           // octant
  int dst = blockIdx.x * 4 + wave;   // 5000*4 == 20000 exactly

  const float* pd = P + (size_t)dst * 32;
  float4 pd4 = *(const float4*)(pd + 4 * h);   // as,z0,z1,ad of dst
  float ad = pd4.w;
  unsigned deg = cnt[dst];
  unsigned rv = list[(size_t)dst * BUCKET + lane];

  float accd = 0.f, acc0 = 0.f, acc1 = 0.f;
  if (o == 0) {   // self-loop: src = dst
    float v = pd4.x + ad;
    v = (v > 0.f) ? v : SLOPE * v;
    float ex = __expf(v);
    accd = ex;
    acc0 = ex * pd4.y;
    acc1 = ex * pd4.z;
  }

  unsigned e0 = o, e1 = o + 8, e2 = o + 16, e3 = o + 24;
  unsigned s0 = __shfl(rv, (int)e0);
  unsigned s1 = __shfl(rv, (int)e1);
  unsigned s2 = __shfl(rv, (int)e2);
  unsigned s3 = __shfl(rv, (int)e3);
  bool m0 = e0 < deg, m1 = e1 < deg, m2 = e2 < deg, m3 = e3 < deg;
  unsigned a0 = m0 ? s0 : (unsigned)dst;
  unsigned a1 = m1 ? s1 : (unsigned)dst;
  unsigned a2 = m2 ? s2 : (unsigned)dst;
  unsigned a3 = m3 ? s3 : (unsigned)dst;
  float4 q0 = *(const float4*)(P + (size_t)a0 * 32 + 4 * h);
  float4 q1 = *(const float4*)(P + (size_t)a1 * 32 + 4 * h);
  float4 q2 = *(const float4*)(P + (size_t)a2 * 32 + 4 * h);
  float4 q3 = *(const float4*)(P + (size_t)a3 * 32 + 4 * h);
  if (m0) {
    float v = q0.x + ad; v = (v > 0.f) ? v : SLOPE * v;
    float ex = __expf(v);
    accd += ex; acc0 = fmaf(ex, q0.y, acc0); acc1 = fmaf(ex, q0.z, acc1);
  }
  if (m1) {
    float v = q1.x + ad; v = (v > 0.f) ? v : SLOPE * v;
    float ex = __expf(v);
    accd += ex; acc0 = fmaf(ex, q1.y, acc0); acc1 = fmaf(ex, q1.z, acc1);
  }
  if (m2) {
    float v = q2.x + ad; v = (v > 0.f) ? v : SLOPE * v;
    float ex = __expf(v);
    accd += ex; acc0 = fmaf(ex, q2.y, acc0); acc1 = fmaf(ex, q2.z, acc1);
  }
  if (m3) {
    float v = q3.x + ad; v = (v > 0.f) ? v : SLOPE * v;
    float ex = __expf(v);
    accd += ex; acc0 = fmaf(ex, q3.y, acc0); acc1 = fmaf(ex, q3.z, acc1);
  }
  if (deg > 32u) {
    unsigned iters = (deg - 32u + 7u) >> 3;
    unsigned e = 32u + (unsigned)o;
    for (unsigned i = 0; i < iters; ++i, e += 8u) {
      unsigned src = __shfl(rv, (int)e);   // all lanes active
      if (e < deg) {
        float4 q = *(const float4*)(P + (size_t)src * 32 + 4 * h);
        float v = q.x + ad; v = (v > 0.f) ? v : SLOPE * v;
        float ex = __expf(v);
        accd += ex; acc0 = fmaf(ex, q.y, acc0); acc1 = fmaf(ex, q.z, acc1);
      }
    }
  }
  float accd_tot = accd + __shfl_xor(accd, 8);
  accd_tot += __shfl_xor(accd_tot, 16);
  accd_tot += __shfl_xor(accd_tot, 32);
  float rcp = 1.0f / accd_tot;
  float r0 = acc0 * rcp;
  float r1 = acc1 * rcp;
#pragma unroll
  for (int m = 1; m < 64; m <<= 1) {
    r0 += __shfl_xor(r0, m);
    r1 += __shfl_xor(r1, m);
  }
  if (lane == 0) {
    ((float2*)out)[dst] = make_float2(cbias[0] + r0, cbias[1] + r1);
  }
}

extern "C" void kernel_launch(void* const* d_in, const int* in_sizes, int n_in,
                              void* d_out, int out_size, void* d_ws, size_t ws_size,
                              hipStream_t stream) {
  const float* x       = (const float*)d_in[0];
  const int*   ei      = (const int*)d_in[1];
  const float* W       = (const float*)d_in[2];
  const float* att_src = (const float*)d_in[3];
  const float* att_dst = (const float*)d_in[4];
  const float* bias    = (const float*)d_in[5];
  const float* fc_w    = (const float*)d_in[6];
  const float* fc_b    = (const float*)d_in[7];
  float* out = (float*)d_out;

  // Workspace layout (4B units):
  // U[4096] | cbias[2]+pad(to 8192) | P[640000] | cnt[20000] | list[20000*64]
  float*    U     = (float*)d_ws;
  float*    cbias = U + 4096;
  float*    P     = U + 8192;
  unsigned* cnt   = (unsigned*)(P + (size_t)NN * 32);
  unsigned* list  = cnt + NN;

  prep_kernel<<<257, 256, 0, stream>>>(W, att_src, att_dst, bias, fc_w, fc_b, U, cbias, cnt);
  scatter_kernel<<<1250, 256, 0, stream>>>(ei, cnt, list);
  proj_kernel<<<625, 128, 0, stream>>>(x, U, P);
  gather_kernel<<<NN / 4, 256, 0, stream>>>(cnt, list, P, cbias, out);
}

// Round 16
// 38.710 us; speedup vs baseline: 1.1956x; 1.1956x over previous
//
#include <hip/hip_runtime.h>

// Problem constants (match reference)
#define NN    20000
#define EDGES 320000
#define HH    8
#define CC    120
#define HC    960
#define SLOPE 0.2f
#define BUCKET 64     // max in-degree bound (Poisson(16); P(>64) ~ 1e-20)
#define NB    64      // counting-sort chunks
#define CH    (EDGES / NB)   // 5000 edges per chunk
#define NPAIR (NN / 2)       // 10000 packed dst pairs

// U column layout (per k row of U[128][32]):  c = 4h+0 -> W_h@att_src[h] (as)
//   c = 4h+1 -> W_h@fc_w[:,0] slice h (z0);  c = 4h+2 -> W_h@fc_w[:,1] (z1)
//   c = 4h+3 -> W_h@att_dst[h] (ad)
// => P row n: [as,z0,z1,ad] x 8 heads; gather reads ONE float4 per (edge,head).
//
// Bucketing = counting sort with RANK STORED DURING HISTOGRAM (the LDS
// atomicAdd's return value IS the within-chunk rank) -> the place phase is
// pure loads/stores: slot = base[chunk][dst] + rank[e].  ZERO global atomics,
// no LDS staging in place, every phase >= 320K-way parallel.

// ---------------------------------------------------------------------------
// K1 prep + hist+rank: grid 321 x 256.
//   blocks 0..255: U (one wave per (h,k)); block 256: cbias;
//   blocks 257..320: chunk c = b-257: LDS histogram of dsts, rank[e] saved.
// ---------------------------------------------------------------------------
__global__ __launch_bounds__(256) void prep_kernel(const float* __restrict__ W,
                                                   const float* __restrict__ att_src,
                                                   const float* __restrict__ att_dst,
                                                   const float* __restrict__ bias,
                                                   const float* __restrict__ fc_w,
                                                   const float* __restrict__ fc_b,
                                                   const int* __restrict__ ei,
                                                   float* __restrict__ U,
                                                   float* __restrict__ cbias,
                                                   unsigned* __restrict__ hist,
                                                   unsigned* __restrict__ rank) {
  __shared__ unsigned hsh[NPAIR];    // 40 KB packed u16 counts
  int t = threadIdx.x, b = blockIdx.x;
  int l = t & 63;
  if (b < 256) {
    int p = b * 4 + (t >> 6);        // 0..1023
    int k = p >> 3, h = p & 7;
    const float* wrow = W + (size_t)k * HC + h * CC;
    const float* asv  = att_src + h * CC;
    const float* adv  = att_dst + h * CC;
    const float2* fv  = (const float2*)fc_w + h * CC;
    bool tail = (l < CC - 64);       // l < 56
    float w0 = wrow[l],            w1 = tail ? wrow[64 + l] : 0.f;
    float s0 = asv[l],             s1 = tail ? asv[64 + l] : 0.f;
    float d0 = adv[l],             d1 = tail ? adv[64 + l] : 0.f;
    float2 f0 = fv[l];
    float2 f1 = tail ? fv[64 + l] : make_float2(0.f, 0.f);
    float a_s = w0 * s0 + w1 * s1;
    float a_d = w0 * d0 + w1 * d1;
    float z0  = w0 * f0.x + w1 * f1.x;
    float z1  = w0 * f0.y + w1 * f1.y;
#pragma unroll
    for (int m = 1; m < 64; m <<= 1) {
      a_s += __shfl_xor(a_s, m);
      a_d += __shfl_xor(a_d, m);
      z0  += __shfl_xor(z0, m);
      z1  += __shfl_xor(z1, m);
    }
    if (l == 0) {
      float* u = U + k * 32 + 4 * h;
      u[0] = a_s; u[1] = z0; u[2] = z1; u[3] = a_d;
    }
  } else if (b == 256) {
    if (t < 128) {
      int j = t >> 6;                // 0 or 1
      float acc = 0.f;
      for (int m = l; m < HC; m += 64) acc = fmaf(bias[m], fc_w[m * 2 + j], acc);
#pragma unroll
      for (int m = 1; m < 64; m <<= 1) acc += __shfl_xor(acc, m);
      if (l == 0) cbias[j] = acc + fc_b[j];
    }
  } else {
    int c = b - 257;                 // chunk 0..63
    for (int i = t; i < NPAIR; i += 256) hsh[i] = 0u;
    __syncthreads();
    const int* dsts = ei + EDGES + c * CH;
    unsigned* rnk = rank + c * CH;
    for (int i = t; i < CH; i += 256) {
      int d = dsts[i];
      unsigned old = atomicAdd(&hsh[d >> 1], (d & 1) ? (1u << 16) : 1u);
      rnk[i] = (d & 1) ? (old >> 16) : (old & 0xFFFFu);
    }
    __syncthreads();
    unsigned* hrow = hist + (size_t)c * NPAIR;
    for (int i = t; i < NPAIR; i += 256) hrow[i] = hsh[i];
  }
}

// ---------------------------------------------------------------------------
// K2 scan: grid 40 x 256.  Thread owns dst-pair column j; walks 64 chunks.
// Writes base[c][j] (exclusive prefix, packed u16) and deg[2j], deg[2j+1].
// ---------------------------------------------------------------------------
__global__ __launch_bounds__(256) void scan_kernel(const unsigned* __restrict__ hist,
                                                   unsigned* __restrict__ base,
                                                   unsigned* __restrict__ deg) {
  int j = blockIdx.x * 256 + threadIdx.x;
  if (j >= NPAIR) return;
  unsigned sA = 0, sB = 0;
#pragma unroll 8
  for (int c = 0; c < NB; ++c) {
    unsigned v = hist[(size_t)c * NPAIR + j];
    base[(size_t)c * NPAIR + j] = sA | (sB << 16);
    sA += v & 0xFFFFu;
    sB += v >> 16;
  }
  deg[2 * j]     = sA;
  deg[2 * j + 1] = sB;
}

// ---------------------------------------------------------------------------
// K3 proj + place.  Grid 1875 x 128.
//   blocks 0..624: proj (R12 verbatim: 32 nodes, 8 outputs/thread).
//   blocks 625..1874: place, 2 edges/thread, NO LDS / NO atomics:
//     slot = base[e/CH][dst] + rank[e];  list[dst*64+slot] = src.
// ---------------------------------------------------------------------------
#define XSTR 132
__global__ __launch_bounds__(128) void projplace_kernel(const float* __restrict__ x,
                                                        const float* __restrict__ U,
                                                        const int* __restrict__ ei,
                                                        const unsigned* __restrict__ base,
                                                        const unsigned* __restrict__ rank,
                                                        unsigned* __restrict__ list,
                                                        float* __restrict__ P) {
  int t = threadIdx.x;
  int b = blockIdx.x;

  if (b >= 625) {
    int e0 = (b - 625) * 256 + t;    // 1250 blocks * 256 = 320000 exactly
#pragma unroll
    for (int j = 0; j < 2; ++j) {
      int e = e0 + j * 128;
      int d = ei[EDGES + e];
      unsigned r = rank[e];
      unsigned c = (unsigned)e / (unsigned)CH;
      unsigned packed = base[(size_t)c * NPAIR + (d >> 1)];
      unsigned bs = (d & 1) ? (packed >> 16) : (packed & 0xFFFFu);
      list[(size_t)d * BUCKET + bs + r] = (unsigned)ei[e];
    }
    return;
  }

  __shared__ float xs[32 * XSTR];    // 32 rows x 128 (+4 pad)
  __shared__ float Us[128 * 32];
  int n0 = b * 32;
  const float4* xg = (const float4*)(x + (size_t)n0 * 128);
  const float4* U4 = (const float4*)U;
  float4 xv[8], uv[8];
#pragma unroll
  for (int j = 0; j < 8; ++j) xv[j] = xg[t + j * 128];
#pragma unroll
  for (int j = 0; j < 8; ++j) uv[j] = U4[t + j * 128];
#pragma unroll
  for (int j = 0; j < 8; ++j) {
    int i = t + j * 128;
    *(float4*)(xs + (i >> 5) * XSTR + (i & 31) * 4) = xv[j];
    ((float4*)Us)[i] = uv[j];
  }
  __syncthreads();

  int rq = t >> 3, cq = t & 7;       // rows {rq, rq+16}, col-quad cq
  float a00 = 0.f, a01 = 0.f, a02 = 0.f, a03 = 0.f;
  float a10 = 0.f, a11 = 0.f, a12 = 0.f, a13 = 0.f;
  const float* xr0 = xs + rq * XSTR;
  const float* xr1 = xs + (rq + 16) * XSTR;
#pragma unroll 4
  for (int k4 = 0; k4 < 32; ++k4) {
    float4 xa = *(const float4*)(xr0 + k4 * 4);
    float4 xb = *(const float4*)(xr1 + k4 * 4);
    float4 u0 = *(const float4*)(Us + (k4 * 4 + 0) * 32 + 4 * cq);
    float4 u1 = *(const float4*)(Us + (k4 * 4 + 1) * 32 + 4 * cq);
    float4 u2 = *(const float4*)(Us + (k4 * 4 + 2) * 32 + 4 * cq);
    float4 u3 = *(const float4*)(Us + (k4 * 4 + 3) * 32 + 4 * cq);
    a00 = fmaf(xa.x, u0.x, a00); a01 = fmaf(xa.x, u0.y, a01);
    a02 = fmaf(xa.x, u0.z, a02); a03 = fmaf(xa.x, u0.w, a03);
    a10 = fmaf(xb.x, u0.x, a10); a11 = fmaf(xb.x, u0.y, a11);
    a12 = fmaf(xb.x, u0.z, a12); a13 = fmaf(xb.x, u0.w, a13);
    a00 = fmaf(xa.y, u1.x, a00); a01 = fmaf(xa.y, u1.y, a01);
    a02 = fmaf(xa.y, u1.z, a02); a03 = fmaf(xa.y, u1.w, a03);
    a10 = fmaf(xb.y, u1.x, a10); a11 = fmaf(xb.y, u1.y, a11);
    a12 = fmaf(xb.y, u1.z, a12); a13 = fmaf(xb.y, u1.w, a13);
    a00 = fmaf(xa.z, u2.x, a00); a01 = fmaf(xa.z, u2.y, a01);
    a02 = fmaf(xa.z, u2.z, a02); a03 = fmaf(xa.z, u2.w, a03);
    a10 = fmaf(xb.z, u2.x, a10); a11 = fmaf(xb.z, u2.y, a11);
    a12 = fmaf(xb.z, u2.z, a12); a13 = fmaf(xb.z, u2.w, a13);
    a00 = fmaf(xa.w, u3.x, a00); a01 = fmaf(xa.w, u3.y, a01);
    a02 = fmaf(xa.w, u3.z, a02); a03 = fmaf(xa.w, u3.w, a03);
    a10 = fmaf(xb.w, u3.x, a10); a11 = fmaf(xb.w, u3.y, a11);
    a12 = fmaf(xb.w, u3.z, a12); a13 = fmaf(xb.w, u3.w, a13);
  }
  *(float4*)(P + (size_t)(n0 + rq) * 32 + 4 * cq) =
      make_float4(a00, a01, a02, a03);
  *(float4*)(P + (size_t)(n0 + rq + 16) * 32 + 4 * cq) =
      make_float4(a10, a11, a12, a13);
}

// ---------------------------------------------------------------------------
// K4 gather: ONE WAVE per dst (R12 verbatim; deg from counting sort).
// ---------------------------------------------------------------------------
__global__ __launch_bounds__(256) void gather_kernel(const unsigned* __restrict__ deg_,
                                                     const unsigned* __restrict__ list,
                                                     const float* __restrict__ P,
                                                     const float* __restrict__ cbias,
                                                     float* __restrict__ out) {
  int t = threadIdx.x;
  int wave = t >> 6;           // 0..3
  int lane = t & 63;
  int h = lane & 7;            // head
  int o = lane >> 3;           // octant
  int dst = blockIdx.x * 4 + wave;   // 5000*4 == 20000 exactly

  const float* pd = P + (size_t)dst * 32;
  float4 pd4 = *(const float4*)(pd + 4 * h);   // as,z0,z1,ad of dst
  float ad = pd4.w;
  unsigned deg = deg_[dst];
  unsigned rv = list[(size_t)dst * BUCKET + lane];

  float accd = 0.f, acc0 = 0.f, acc1 = 0.f;
  if (o == 0) {   // self-loop: src = dst
    float v = pd4.x + ad;
    v = (v > 0.f) ? v : SLOPE * v;
    float ex = __expf(v);
    accd = ex;
    acc0 = ex * pd4.y;
    acc1 = ex * pd4.z;
  }

  unsigned e0 = o, e1 = o + 8, e2 = o + 16, e3 = o + 24;
  unsigned s0 = __shfl(rv, (int)e0);
  unsigned s1 = __shfl(rv, (int)e1);
  unsigned s2 = __shfl(rv, (int)e2);
  unsigned s3 = __shfl(rv, (int)e3);
  bool m0 = e0 < deg, m1 = e1 < deg, m2 = e2 < deg, m3 = e3 < deg;
  unsigned a0 = m0 ? s0 : (unsigned)dst;
  unsigned a1 = m1 ? s1 : (unsigned)dst;
  unsigned a2 = m2 ? s2 : (unsigned)dst;
  unsigned a3 = m3 ? s3 : (unsigned)dst;
  float4 q0 = *(const float4*)(P + (size_t)a0 * 32 + 4 * h);
  float4 q1 = *(const float4*)(P + (size_t)a1 * 32 + 4 * h);
  float4 q2 = *(const float4*)(P + (size_t)a2 * 32 + 4 * h);
  float4 q3 = *(const float4*)(P + (size_t)a3 * 32 + 4 * h);
  if (m0) {
    float v = q0.x + ad; v = (v > 0.f) ? v : SLOPE * v;
    float ex = __expf(v);
    accd += ex; acc0 = fmaf(ex, q0.y, acc0); acc1 = fmaf(ex, q0.z, acc1);
  }
  if (m1) {
    float v = q1.x + ad; v = (v > 0.f) ? v : SLOPE * v;
    float ex = __expf(v);
    accd += ex; acc0 = fmaf(ex, q1.y, acc0); acc1 = fmaf(ex, q1.z, acc1);
  }
  if (m2) {
    float v = q2.x + ad; v = (v > 0.f) ? v : SLOPE * v;
    float ex = __expf(v);
    accd += ex; acc0 = fmaf(ex, q2.y, acc0); acc1 = fmaf(ex, q2.z, acc1);
  }
  if (m3) {
    float v = q3.x + ad; v = (v > 0.f) ? v : SLOPE * v;
    float ex = __expf(v);
    accd += ex; acc0 = fmaf(ex, q3.y, acc0); acc1 = fmaf(ex, q3.z, acc1);
  }
  if (deg > 32u) {
    unsigned iters = (deg - 32u + 7u) >> 3;
    unsigned e = 32u + (unsigned)o;
    for (unsigned i = 0; i < iters; ++i, e += 8u) {
      unsigned src = __shfl(rv, (int)e);   // all lanes active
      if (e < deg) {
        float4 q = *(const float4*)(P + (size_t)src * 32 + 4 * h);
        float v = q.x + ad; v = (v > 0.f) ? v : SLOPE * v;
        float ex = __expf(v);
        accd += ex; acc0 = fmaf(ex, q.y, acc0); acc1 = fmaf(ex, q.z, acc1);
      }
    }
  }
  float accd_tot = accd + __shfl_xor(accd, 8);
  accd_tot += __shfl_xor(accd_tot, 16);
  accd_tot += __shfl_xor(accd_tot, 32);
  float rcp = 1.0f / accd_tot;
  float r0 = acc0 * rcp;
  float r1 = acc1 * rcp;
#pragma unroll
  for (int m = 1; m < 64; m <<= 1) {
    r0 += __shfl_xor(r0, m);
    r1 += __shfl_xor(r1, m);
  }
  if (lane == 0) {
    ((float2*)out)[dst] = make_float2(cbias[0] + r0, cbias[1] + r1);
  }
}

extern "C" void kernel_launch(void* const* d_in, const int* in_sizes, int n_in,
                              void* d_out, int out_size, void* d_ws, size_t ws_size,
                              hipStream_t stream) {
  const float* x       = (const float*)d_in[0];
  const int*   ei      = (const int*)d_in[1];
  const float* W       = (const float*)d_in[2];
  const float* att_src = (const float*)d_in[3];
  const float* att_dst = (const float*)d_in[4];
  const float* bias    = (const float*)d_in[5];
  const float* fc_w    = (const float*)d_in[6];
  const float* fc_b    = (const float*)d_in[7];
  float* out = (float*)d_out;

  // Workspace layout (4B units):
  // U[4096] | cbias[2]+pad(to 8192) | P[640000] | deg[20000] | list[1280000] |
  // hist[64*10000] | base[64*10000] | rank[320000]
  float*    U     = (float*)d_ws;
  float*    cbias = U + 4096;
  float*    P     = U + 8192;
  unsigned* deg   = (unsigned*)(P + (size_t)NN * 32);
  unsigned* list  = deg + NN;
  unsigned* hist  = list + (size_t)NN * BUCKET;
  unsigned* base  = hist + (size_t)NB * NPAIR;
  unsigned* rank  = base + (size_t)NB * NPAIR;

  prep_kernel<<<321, 256, 0, stream>>>(W, att_src, att_dst, bias, fc_w, fc_b,
                                       ei, U, cbias, hist, rank);
  scan_kernel<<<40, 256, 0, stream>>>(hist, base, deg);
  projplace_kernel<<<1875, 128, 0, stream>>>(x, U, ei, base, rank, list, P);
  gather_kernel<<<NN / 4, 256, 0, stream>>>(deg, list, P, cbias, out);
}